// Round 5
// baseline (312.773 us; speedup 1.0000x reference)
//
#include <hip/hip_runtime.h>
#include <stdint.h>

// ---------------- problem constants ----------------
#define BATCH 16
#define NCLS 80
#define NPOS 21824            // 16384+4096+1024+256+64
#define POOLN 3320            // 1000+1000+1000+256+64
#define MAXDET 100

// superset segment capacities (multiples of 8)
#define CAP0 4096
#define CAP1 2432
#define CAP2 1024
#define C34 320
#define CAP34 320
#define SEG1 (CAP0)                    // 4096
#define SEG2 (CAP0 + CAP1)             // 6528
#define SEG3 (CAP0 + CAP1 + CAP2)      // 7552
#define CAPTOT (SEG3 + CAP34)          // 7872

#define DEC_BPI 341                    // 21824/64 anchors-per-block blocks per image
#define GATHER_BPI 16                  // 16 x 1344 = 21504 anchors (levels 0..2)
#define GATHER_CHUNK 1344              // multiple of 64 -> wave-uniform level
#define POS_BPI 13                     // 13 x 256 = 3328 >= 3320 pool elements

#define NBINS 4096                     // digit = nsb >> 20 (12-bit key prefix)
#define HIST_TPI 11                    // hist tasks per image: 8(l0) + 2(l1) + 1(l2)

__device__ const int d_lvl_off[5] = {0, 16384, 20480, 21504, 21760};
__device__ const int d_lvl_hw[5]  = {16384, 4096, 1024, 256, 64};

struct Ptrs { const float* p[20]; };

__device__ __forceinline__ void map_lvl(int r, int& level, int& hw) {
  if      (r < 16384) { level = 0; hw = r; }
  else if (r < 20480) { level = 1; hw = r - 16384; }
  else if (r < 21504) { level = 2; hw = r - 20480; }
  else if (r < 21760) { level = 3; hw = r - 21504; }
  else                { level = 4; hw = r - 21760; }
}

// key = (nsb)<<32 | (level<<20) | hw with nsb = ~score_bits; ascending ==
// (score desc, level asc, idx asc). Unique per image; ~0ULL is a strictly-greater
// sentinel. digit = nsb >> 20 is a 12-bit key PREFIX -> {digit <= B} downward-closed.

// ---------------- kernel 1: decode, fully-coalesced two-phase argmax -----------
// Phase 1: the block's 64 anchors are 1280 contiguous float4s of cls; thread t
// loads c4[t+256w] (1024B/instr, perfectly coalesced) and writes each chunk's
// first-occurrence argmax (strict >, ascending j == ascending class idx) to LDS.
// Phase 2: 4 threads/anchor fold chunks q=5r..5r+4 ascending with
// (> || (== && lower idx)) then shfl_xor(1,2) — comparison-for-comparison
// identical to the old per-part 20-chain + combine. Epilogue unchanged.
__global__ __launch_bounds__(256) void decode_kernel(Ptrs args, uint4* __restrict__ dec,
                                                     unsigned long long* __restrict__ gbuf,
                                                     int* __restrict__ gcnt,
                                                     unsigned* __restrict__ sbuf) {
  __shared__ float2 sm[1280];               // (chunk max, chunk argmax-bits), 10 KB
  int b  = blockIdx.x / DEC_BPI;
  int bb = blockIdx.x - b * DEC_BPI;
  int t = threadIdx.x;
  if (bb == 0 && t < 3) gcnt[b * 3 + t] = 0;

  int flat0 = bb * 64;                      // level boundaries are all multiples of 64
  int level, hw0;
  map_lvl(flat0, level, hw0);
  int HW = d_lvl_hw[level];

  const float* cls = args.p[level * 4 + 0];
  const float* reg = args.p[level * 4 + 1];
  const float* ctr = args.p[level * 4 + 2];
  const float* pos = args.p[level * 4 + 3];

  // ---- phase 1: coalesced load + per-chunk argmax ----
  const float4* c4 = (const float4*)(cls + ((long)b * HW + hw0) * NCLS);
#pragma unroll
  for (int w = 0; w < 5; ++w) {
    int f = t + 256 * w;                    // float4 index in [0,1280)
    float4 v = c4[f];
    int q = f % 20;                         // chunk within anchor -> classes 4q..4q+3
    float m = -1e30f; int am = 4 * q;
    if (v.x > m) { m = v.x; am = 4 * q + 0; }
    if (v.y > m) { m = v.y; am = 4 * q + 1; }
    if (v.z > m) { m = v.z; am = 4 * q + 2; }
    if (v.w > m) { m = v.w; am = 4 * q + 3; }
    sm[f] = make_float2(m, __int_as_float(am));
  }
  __syncthreads();

  // ---- phase 2: fold 5 chunks per lane (ascending), then 4-lane shfl combine ----
  int aoff = t >> 2, r = t & 3;
  int base = aoff * 20 + 5 * r;
  float2 c0 = sm[base];
  float m = c0.x; int am = __float_as_int(c0.y);
#pragma unroll
  for (int i = 1; i < 5; ++i) {
    float2 cc = sm[base + i];
    int oa = __float_as_int(cc.y);
    if (cc.x > m || (cc.x == m && oa < am)) { m = cc.x; am = oa; }
  }
#pragma unroll
  for (int d = 1; d <= 2; d <<= 1) {
    float om = __shfl_xor(m, d, 64);
    int   oa = __shfl_xor(am, d, 64);
    if (om > m || (om == m && oa < am)) { m = om; am = oa; }
  }

  if (r == 0) {
    int hw = hw0 + aoff;
    long abase = (long)b * HW + hw;
    float4 rg = *(const float4*)(reg + abase * 4);
    float  ct = ctr[abase];
    float2 ps = ((const float2*)pos)[abase];

    float e0 = expf(rg.x), e1 = expf(rg.y), e2 = expf(rg.z), e3 = expf(rg.w);
    int x1 = (int)(ps.x - e0);   // C truncation == .astype(int32)
    int y1 = (int)(ps.y - e1);
    int x2 = (int)(ps.x + e2);
    int y2 = (int)(ps.y + e3);
    x1 = max(x1, 0); y1 = max(y1, 0);
    x2 = min(x2, 1023); y2 = min(y2, 1023);

    float sigm = 1.0f / (1.0f + expf(-m));
    float sigc = 1.0f / (1.0f + expf(-ct));
    float score = sqrtf(sigm * sigc);

    uint4 e;
    e.x = __float_as_uint(score);
    e.y = (unsigned)am;
    e.z = (unsigned)(x1 & 0xFFFF) | ((unsigned)y1 << 16);
    e.w = (unsigned)(x2 & 0xFFFF) | ((unsigned)y2 << 16);
    dec[b * NPOS + flat0 + aoff] = e;

    unsigned nsb = ~e.x;
    sbuf[b * NPOS + flat0 + aoff] = nsb;
    if (level >= 3) {    // deterministic slots for complete levels 3/4
      unsigned long long key =
          ((unsigned long long)nsb << 32) | (unsigned)((level << 20) | hw);
      gbuf[(size_t)b * CAPTOT + SEG3 + ((level == 3) ? hw : 256 + hw)] = key;
    }
  }
}

// ---------------- kernel 2: wide histogram (LDS-local, merge nonzero bins) ------
__global__ __launch_bounds__(256) void hist_kernel(const unsigned* __restrict__ sbuf,
                                                   unsigned* __restrict__ ghist) {
  __shared__ unsigned h[NBINS];
  int img = blockIdx.x / HIST_TPI, task = blockIdx.x % HIST_TPI;
  int level, start, n;
  if      (task < 8)  { level = 0; start = task * 2048;       n = 2048; }
  else if (task < 10) { level = 1; start = (task - 8) * 2048; n = 2048; }
  else                { level = 2; start = 0;                 n = 1024; }
  int tid = threadIdx.x;

  for (int i = tid; i < NBINS; i += 256) h[i] = 0;
  __syncthreads();
  const unsigned* base = sbuf + img * NPOS + d_lvl_off[level] + start;
  for (int i = tid; i < n; i += 256)
    atomicAdd(&h[base[i] >> 20], 1u);
  __syncthreads();
  unsigned* gh = ghist + (unsigned)(img * 3 + level) * NBINS;
  for (int i = tid; i < NBINS; i += 256) {
    unsigned v = h[i];
    if (v) atomicAdd(&gh[i], v);
  }
}

// ---------------- kernel 3: cutoff (parallel scan; proven R7 logic, 4096 bins) ----
__global__ __launch_bounds__(256) void cutoff_kernel(const unsigned* __restrict__ ghist,
                                                     int* __restrict__ bcut) {
  __shared__ unsigned wpart[4];
  __shared__ int shB;
  int img = blockIdx.x / 3, level = blockIdx.x % 3;
  const unsigned* h = ghist + (unsigned)(img * 3 + level) * NBINS;
  int tid = threadIdx.x, lane = tid & 63, wv = tid >> 6;

  unsigned hl[16];
  unsigned s = 0;
#pragma unroll
  for (int k = 0; k < 16; ++k) { hl[k] = h[16 * tid + k]; s += hl[k]; }
  unsigned incl = s;
  for (int d = 1; d < 64; d <<= 1) {
    unsigned v = __shfl_up(incl, d, 64);
    if (lane >= d) incl += v;
  }
  if (lane == 63) wpart[wv] = incl;
  __syncthreads();
  unsigned woff = 0;
  for (int w = 0; w < wv; ++w) woff += wpart[w];
  unsigned excl = woff + incl - s;
  if (excl < 1000u && excl + s >= 1000u) {       // unique crossing thread (N >= 1000)
    unsigned cum = excl; int B = NBINS - 1;
#pragma unroll
    for (int k = 0; k < 16; ++k) {
      cum += hl[k];
      if (cum >= 1000u) { B = 16 * tid + k; break; }
    }
    shB = B;
  }
  __syncthreads();
  if (tid == 0) bcut[img * 3 + level] = shB;
}

// ---------------- kernel 4: wide gather -> single gbuf layout (proven R7) ------
__global__ __launch_bounds__(256) void gather_kernel(const unsigned* __restrict__ sbuf,
                                                     const int* __restrict__ bcut,
                                                     unsigned long long* __restrict__ gbuf,
                                                     int* __restrict__ gcnt) {
  int img = blockIdx.x / GATHER_BPI, bb = blockIdx.x % GATHER_BPI;
  int tid = threadIdx.x, lane = tid & 63;
  int start = bb * GATHER_CHUNK;
  int b0 = bcut[img * 3 + 0], b1 = bcut[img * 3 + 1], b2 = bcut[img * 3 + 2];
  unsigned long long* gb = gbuf + (size_t)img * CAPTOT;

  for (int j = start + tid; j < start + GATHER_CHUNK; j += 256) {
    int level, hw;
    map_lvl(j, level, hw);                       // level wave-uniform (64-aligned groups)
    unsigned nsb = sbuf[img * NPOS + j];
    bool sel = (int)(nsb >> 20) <= ((level == 0) ? b0 : (level == 1) ? b1 : b2);
    unsigned long long msk = __ballot(sel);
    if (msk) {
      int nsel = __popcll(msk);
      int bas = 0;
      if (lane == 0) bas = atomicAdd(&gcnt[img * 3 + level], nsel);
      bas = __shfl(bas, 0, 64);
      if (sel) {
        int p = bas + __popcll(msk & ((1ULL << lane) - 1ULL));
        int cap   = (level == 0) ? CAP0 : (level == 1) ? CAP1 : CAP2;
        int sbase = (level == 0) ? 0    : (level == 1) ? SEG1 : SEG2;
        unsigned long long key =
            ((unsigned long long)nsb << 32) | (unsigned)((level << 20) | hw);
        if (p < cap) gb[sbase + p] = key;
      }
    }
  }
}

// ---------------- kernel 5a: register-blocked bitonic sort (V=16/thread) -------
// Same comparator / sentinel semantics as before, so the result is bit-identical;
// only the schedule changed. j<16 stages: in-register (no barriers). 16<=j<=512:
// __shfl_xor exchange (same wave, no barriers). j in {1024,2048}: LDS exchange
// (<=3 phases total). Network size adapts: Pnet = next pow2 >= c (>=512).
#define SWQ(q) ((q) ^ (((q) >> 3) & 7))          // pair-index XOR swizzle (bijective)

__device__ __forceinline__ void cmpswap(unsigned long long& a, unsigned long long& b,
                                        bool asc) {
  unsigned long long mn = a < b ? a : b;
  unsigned long long mx = a < b ? b : a;
  a = asc ? mn : mx;
  b = asc ? mx : mn;
}

__global__ __launch_bounds__(256) void sort_kernel(unsigned long long* __restrict__ gbuf,
                                                   const int* __restrict__ gcnt) {
  __shared__ ulonglong2 lds2[2048];              // 4096 u64 = 32 KiB
  int img = blockIdx.x >> 2, sg = blockIdx.x & 3;
  int t = threadIdx.x;
  unsigned long long* gb = gbuf + (size_t)img * CAPTOT;

  int base, cap;
  if      (sg == 0) { base = 0;    cap = CAP0; }
  else if (sg == 1) { base = SEG1; cap = CAP1; }
  else if (sg == 2) { base = SEG2; cap = CAP2; }
  else              { base = SEG3; cap = C34;  }
  int c = (sg < 3) ? min(gcnt[img * 3 + sg], cap) : C34;

  int Pnet = 512;
  while (Pnet < c) Pnet <<= 1;                   // <= 4096

  // ---- stage in: global -> LDS (coalesced, sentinel-padded) -> regs ----
  for (int q = t; q < (Pnet >> 1); q += 256) {
    int e0 = 2 * q;
    ulonglong2 val;
    val.x = (e0     < c) ? gb[base + e0]     : ~0ULL;
    val.y = (e0 + 1 < c) ? gb[base + e0 + 1] : ~0ULL;
    lds2[SWQ(q)] = val;
  }
  __syncthreads();

  unsigned long long key[16];
  if (t * 16 < Pnet) {
#pragma unroll
    for (int w = 0; w < 8; ++w) {
      ulonglong2 val = lds2[SWQ(t * 8 + w)];
      key[2 * w]     = val.x;
      key[2 * w + 1] = val.y;
    }
  } else {
#pragma unroll
    for (int v = 0; v < 16; ++v) key[v] = ~0ULL;
  }

  // ---- k = 2,4,8: fully in-register, compile-time directions ----
#pragma unroll
  for (int kk = 2; kk <= 8; kk <<= 1)
#pragma unroll
    for (int j = kk >> 1; j >= 1; j >>= 1)
#pragma unroll
      for (int v = 0; v < 16; ++v)
        if (!(v & j)) cmpswap(key[v], key[v | j], (v & kk) == 0);

  // ---- k = 16 .. Pnet ----
  for (int k = 16; k <= Pnet; k <<= 1) {
    bool asc = (t & (k >> 4)) == 0;              // dir of this thread's whole chunk
    for (int j = k >> 1; j >= 16; j >>= 1) {
      int d = j >> 4;                            // partner thread distance
      bool keep_min = ((t & d) == 0) == asc;
      if (d <= 32) {                             // same wave: shuffle exchange
#pragma unroll
        for (int v = 0; v < 16; ++v) {
          unsigned long long p = __shfl_xor(key[v], d, 64);
          unsigned long long mn = key[v] < p ? key[v] : p;
          unsigned long long mx = key[v] < p ? p : key[v];
          key[v] = keep_min ? mn : mx;
        }
      } else {                                   // cross-wave: LDS exchange
        __syncthreads();
#pragma unroll
        for (int w = 0; w < 8; ++w)
          lds2[SWQ(t * 8 + w)] = make_ulonglong2(key[2 * w], key[2 * w + 1]);
        __syncthreads();
        int tp = t ^ d;
#pragma unroll
        for (int w = 0; w < 8; ++w) {
          ulonglong2 pv = lds2[SWQ(tp * 8 + w)];
          unsigned long long a = key[2 * w], b = key[2 * w + 1];
          unsigned long long mn0 = a < pv.x ? a : pv.x, mx0 = a < pv.x ? pv.x : a;
          unsigned long long mn1 = b < pv.y ? b : pv.y, mx1 = b < pv.y ? pv.y : b;
          key[2 * w]     = keep_min ? mn0 : mx0;
          key[2 * w + 1] = keep_min ? mn1 : mx1;
        }
      }
    }
    // tail j = 8..1: in-register, uniform direction
#pragma unroll
    for (int j = 8; j >= 1; j >>= 1)
#pragma unroll
      for (int v = 0; v < 16; ++v)
        if (!(v & j)) cmpswap(key[v], key[v | j], asc);
  }

  // ---- stage out: regs -> LDS -> global (coalesced) ----
  __syncthreads();
  if (t * 16 < Pnet) {
#pragma unroll
    for (int w = 0; w < 8; ++w)
      lds2[SWQ(t * 8 + w)] = make_ulonglong2(key[2 * w], key[2 * w + 1]);
  }
  __syncthreads();
  int npairs = (c + 1) >> 1;                     // may write one sentinel pad (slot < cap, never read)
  ulonglong2* gb2 = (ulonglong2*)(gb + base);    // base is a multiple of 8 -> 16B aligned
  for (int q = t; q < npairs; q += 256) gb2[q] = lds2[SWQ(q)];
}

// ---------------- kernel 5b: position via binary search -> sorted pool --------
__device__ __forceinline__ int lbound(const unsigned long long* __restrict__ a,
                                      int n, unsigned long long x) {
  int lo = 0, len = n;
  while (len > 0) {
    int half = len >> 1;
    int mid = lo + half;
    if (a[mid] < x) { lo = mid + 1; len -= half + 1; }
    else            { len = half; }
  }
  return lo;
}

__global__ __launch_bounds__(256) void pos_kernel(const unsigned long long* __restrict__ gbuf,
                                                  const int* __restrict__ gcnt,
                                                  unsigned long long* __restrict__ pool) {
  int img = blockIdx.x / POS_BPI, bb = blockIdx.x % POS_BPI;
  int e = bb * 256 + threadIdx.x;
  const unsigned long long* gb = gbuf + (size_t)img * CAPTOT;

  int c0 = min(gcnt[img * 3 + 0], CAP0);
  int c1 = min(gcnt[img * 3 + 1], CAP1);
  int c2 = min(gcnt[img * 3 + 2], CAP2);
  int m0 = min(c0, 1000), m1 = min(c1, 1000), m2 = min(c2, 1000);
  int tot = m0 + m1 + m2 + C34;
  if (e >= tot) return;

  int t, i;
  if      (e < m0)           { t = 0; i = e; }
  else if (e < m0 + m1)      { t = 1; i = e - m0; }
  else if (e < m0 + m1 + m2) { t = 2; i = e - m0 - m1; }
  else                       { t = 3; i = e - m0 - m1 - m2; }

  const int off[4] = {0, SEG1, SEG2, SEG3};
  const int cc[4]  = {c0, c1, c2, C34};

  unsigned long long key = gb[off[t] + i];
  int pos = i;                                   // own-segment term: min(rank,1000)=i
#pragma unroll
  for (int u = 0; u < 4; ++u) {
    if (u == t) continue;
    pos += min(lbound(gb + off[u], cc[u], key), 1000);
  }
  pool[img * POOLN + pos] = key;
}

// ---------------- kernel 6: per-image greedy NMS, 64-wide batched --------------
// Exact greedy semantics (R3-verified): per-lane candidates, kept-list broadcast
// test, ffs-order in-batch resolve, exact integer IoU, sorted-desc early exits.
__global__ __launch_bounds__(64) void nms_kernel(const uint4* __restrict__ dec,
                                                 const unsigned long long* __restrict__ pool,
                                                 float* __restrict__ out) {
  __shared__ int4 kbox[MAXDET];
  __shared__ int  karea[MAXDET];
  int img = blockIdx.x;
  int lane = threadIdx.x;

  float* out_s = out + img * MAXDET;
  float* out_c = out + BATCH * MAXDET + img * MAXDET;
  float* out_b = out + 2 * BATCH * MAXDET + img * MAXDET * 4;

  int k = 0;
  bool full = false;

  for (int b0 = 0; b0 < POOLN; b0 += 64) {
    int i = b0 + lane;
    bool inb = i < POOLN;

    float sc = -1.0f;
    int4 bx = make_int4(0, 0, 0, 0);
    int ar = 0;
    unsigned cls = 0;
    if (inb) {
      unsigned long long key = pool[img * POOLN + i];
      unsigned low = (unsigned)key;
      int level = (low >> 20) & 7;
      int idx = low & 0xFFFFF;
      uint4 e = dec[img * NPOS + d_lvl_off[level] + idx];
      sc = __uint_as_float(e.x);
      cls = e.y;
      bx = make_int4((int)(e.z & 0xFFFF), (int)(e.z >> 16),
                     (int)(e.w & 0xFFFF), (int)(e.w >> 16));
      ar = (bx.z - bx.x) * (bx.w - bx.y);
    }

    bool invalid = !(sc > 0.01f);
    if (__all(invalid)) break;          // sorted desc: everything after is invalid too
    bool sup = invalid;

    // vs previously-kept boxes (uniform LDS broadcasts, independent iterations)
    for (int t = 0; t < k; ++t) {
      int4 kb = kbox[t];
      int  ka = karea[t];
      int xx1 = max(bx.x, kb.x), yy1 = max(bx.y, kb.y);
      int xx2 = min(bx.z, kb.z), yy2 = min(bx.w, kb.w);
      int iw = max(xx2 - xx1, 0), ih = max(yy2 - yy1, 0);
      int inter = iw * ih;
      int uni = ar + ka - inter;
      sup = sup || (((long long)inter << 25) > 20132661LL * (long long)uni);
    }

    // in-batch resolve (ascending lane == ascending sorted index)
    unsigned long long alive = __ballot(!sup);
    while (alive) {
      int j = __ffsll(alive) - 1;

      int jx1 = __shfl(bx.x, j, 64), jy1 = __shfl(bx.y, j, 64);
      int jx2 = __shfl(bx.z, j, 64), jy2 = __shfl(bx.w, j, 64);
      int ja  = __shfl(ar,   j, 64);

      if (lane == j) {                  // lane j is kept: record + emit
        kbox[k]  = bx;
        karea[k] = ar;
        out_s[k] = sc;
        out_c[k] = (float)(int)cls;
        out_b[k * 4 + 0] = (float)bx.x;
        out_b[k * 4 + 1] = (float)bx.y;
        out_b[k * 4 + 2] = (float)bx.z;
        out_b[k * 4 + 3] = (float)bx.w;
      }
      ++k;
      if (k == MAXDET) { full = true; break; }

      if (lane > j) {                   // apply j's suppression to later lanes
        int xx1 = max(bx.x, jx1), yy1 = max(bx.y, jy1);
        int xx2 = min(bx.z, jx2), yy2 = min(bx.w, jy2);
        int iw = max(xx2 - xx1, 0), ih = max(yy2 - yy1, 0);
        int inter = iw * ih;
        int uni = ar + ja - inter;
        sup = sup || (((long long)inter << 25) > 20132661LL * (long long)uni);
      }

      unsigned long long himask = (j < 63) ? (~0ULL << (j + 1)) : 0ULL;
      alive = __ballot(!sup) & himask;
    }
    if (full) break;
  }

  for (int s = k + lane; s < MAXDET; s += 64) {
    out_s[s] = -1.0f;
    out_c[s] = -1.0f;
    out_b[s * 4 + 0] = -1.0f;
    out_b[s * 4 + 1] = -1.0f;
    out_b[s * 4 + 2] = -1.0f;
    out_b[s * 4 + 3] = -1.0f;
  }
}

// ---------------- launcher ----------------
extern "C" void kernel_launch(void* const* d_in, const int* in_sizes, int n_in,
                              void* d_out, int out_size, void* d_ws, size_t ws_size,
                              hipStream_t stream) {
  Ptrs args;
  for (int i = 0; i < 20; ++i) args.p[i] = (const float*)d_in[i];

  char* ws = (char*)d_ws;
  uint4* dec = (uint4*)ws;                              // 5,586,944 B
  ws += (size_t)BATCH * NPOS * 16;
  unsigned long long* pool = (unsigned long long*)ws;   // 424,960 B
  ws += (size_t)BATCH * POOLN * 8;
  unsigned long long* gbuf = (unsigned long long*)ws;   // 1,007,616 B (16B-aligned)
  ws += (size_t)BATCH * CAPTOT * 8;
  unsigned* sbuf = (unsigned*)ws;                       // 16*21824*4 = 1,396,736 B
  ws += (size_t)BATCH * NPOS * 4;
  unsigned* ghist = (unsigned*)ws;                      // 48*4096*4 = 786,432 B
  ws += (size_t)BATCH * 3 * NBINS * 4;
  int* gcnt = (int*)ws;                                 // 192 B  (zeroed by decode)
  ws += 192;
  int* bcut = (int*)ws;                                 // 192 B  (written by cutoff)
  float* out = (float*)d_out;

  hipMemsetAsync(ghist, 0, (size_t)BATCH * 3 * NBINS * 4, stream);

  decode_kernel<<<BATCH * DEC_BPI, 256, 0, stream>>>(args, dec, gbuf, gcnt, sbuf);
  hist_kernel<<<BATCH * HIST_TPI, 256, 0, stream>>>(sbuf, ghist);
  cutoff_kernel<<<BATCH * 3, 256, 0, stream>>>(ghist, bcut);
  gather_kernel<<<BATCH * GATHER_BPI, 256, 0, stream>>>(sbuf, bcut, gbuf, gcnt);
  sort_kernel<<<BATCH * 4, 256, 0, stream>>>(gbuf, gcnt);
  pos_kernel<<<BATCH * POS_BPI, 256, 0, stream>>>(gbuf, gcnt, pool);
  nms_kernel<<<BATCH, 64, 0, stream>>>(dec, pool, out);
}

// Round 6
// 308.398 us; speedup vs baseline: 1.0142x; 1.0142x over previous
//
#include <hip/hip_runtime.h>
#include <stdint.h>

// ---------------- problem constants ----------------
#define BATCH 16
#define NCLS 80
#define NPOS 21824            // 16384+4096+1024+256+64
#define POOLN 3320            // 1000+1000+1000+256+64
#define MAXDET 100

// superset segment capacities (multiples of 8)
#define CAP0 4096
#define CAP1 2432
#define CAP2 1024
#define C34 320
#define SEG1 (CAP0)                    // 4096
#define SEG2 (CAP0 + CAP1)             // 6528
#define SEG3 (CAP0 + CAP1 + CAP2)      // 7552
#define CAPTOT (SEG3 + C34)            // 7872

#define DEC_BPI 341                    // 21824/64 anchors-per-block blocks per image
#define POS_BPI 13                     // 13 x 256 = 3328 >= 3320 pool elements
#define NBINS 4096                     // digit = nsb >> 20 (12-bit key prefix)

__device__ const int d_lvl_off[5] = {0, 16384, 20480, 21504, 21760};
__device__ const int d_lvl_hw[5]  = {16384, 4096, 1024, 256, 64};

struct Ptrs { const float* p[20]; };

__device__ __forceinline__ void map_lvl(int r, int& level, int& hw) {
  if      (r < 16384) { level = 0; hw = r; }
  else if (r < 20480) { level = 1; hw = r - 16384; }
  else if (r < 21504) { level = 2; hw = r - 20480; }
  else if (r < 21760) { level = 3; hw = r - 21504; }
  else                { level = 4; hw = r - 21760; }
}

// key = (nsb)<<32 | (level<<20) | hw with nsb = ~score_bits; ascending ==
// (score desc, level asc, idx asc). Unique per image; ~0ULL is a strictly-greater
// sentinel. digit = nsb >> 20 is a 12-bit key PREFIX -> {digit <= B} downward-closed.

// ---------------- kernel 1: decode (R4 coalesced two-phase argmax, BW-bound) ----
__global__ __launch_bounds__(256) void decode_kernel(Ptrs args, uint4* __restrict__ dec,
                                                     unsigned long long* __restrict__ gbuf,
                                                     unsigned* __restrict__ sbuf) {
  __shared__ float2 sm[1280];               // (chunk max, chunk argmax-bits), 10 KB
  int b  = blockIdx.x / DEC_BPI;
  int bb = blockIdx.x - b * DEC_BPI;
  int t = threadIdx.x;

  int flat0 = bb * 64;                      // level boundaries are all multiples of 64
  int level, hw0;
  map_lvl(flat0, level, hw0);
  int HW = d_lvl_hw[level];

  const float* cls = args.p[level * 4 + 0];
  const float* reg = args.p[level * 4 + 1];
  const float* ctr = args.p[level * 4 + 2];
  const float* pos = args.p[level * 4 + 3];

  // ---- phase 1: coalesced load + per-chunk argmax ----
  const float4* c4 = (const float4*)(cls + ((long)b * HW + hw0) * NCLS);
#pragma unroll
  for (int w = 0; w < 5; ++w) {
    int f = t + 256 * w;                    // float4 index in [0,1280)
    float4 v = c4[f];
    int q = f % 20;                         // chunk within anchor -> classes 4q..4q+3
    float m = -1e30f; int am = 4 * q;
    if (v.x > m) { m = v.x; am = 4 * q + 0; }
    if (v.y > m) { m = v.y; am = 4 * q + 1; }
    if (v.z > m) { m = v.z; am = 4 * q + 2; }
    if (v.w > m) { m = v.w; am = 4 * q + 3; }
    sm[f] = make_float2(m, __int_as_float(am));
  }
  __syncthreads();

  // ---- phase 2: fold 5 chunks per lane (ascending), then 4-lane shfl combine ----
  int aoff = t >> 2, r = t & 3;
  int base = aoff * 20 + 5 * r;
  float2 c0 = sm[base];
  float m = c0.x; int am = __float_as_int(c0.y);
#pragma unroll
  for (int i = 1; i < 5; ++i) {
    float2 cc = sm[base + i];
    int oa = __float_as_int(cc.y);
    if (cc.x > m || (cc.x == m && oa < am)) { m = cc.x; am = oa; }
  }
#pragma unroll
  for (int d = 1; d <= 2; d <<= 1) {
    float om = __shfl_xor(m, d, 64);
    int   oa = __shfl_xor(am, d, 64);
    if (om > m || (om == m && oa < am)) { m = om; am = oa; }
  }

  if (r == 0) {
    int hw = hw0 + aoff;
    long abase = (long)b * HW + hw;
    float4 rg = *(const float4*)(reg + abase * 4);
    float  ct = ctr[abase];
    float2 ps = ((const float2*)pos)[abase];

    float e0 = expf(rg.x), e1 = expf(rg.y), e2 = expf(rg.z), e3 = expf(rg.w);
    int x1 = (int)(ps.x - e0);   // C truncation == .astype(int32)
    int y1 = (int)(ps.y - e1);
    int x2 = (int)(ps.x + e2);
    int y2 = (int)(ps.y + e3);
    x1 = max(x1, 0); y1 = max(y1, 0);
    x2 = min(x2, 1023); y2 = min(y2, 1023);

    float sigm = 1.0f / (1.0f + expf(-m));
    float sigc = 1.0f / (1.0f + expf(-ct));
    float score = sqrtf(sigm * sigc);

    uint4 e;
    e.x = __float_as_uint(score);
    e.y = (unsigned)am;
    e.z = (unsigned)(x1 & 0xFFFF) | ((unsigned)y1 << 16);
    e.w = (unsigned)(x2 & 0xFFFF) | ((unsigned)y2 << 16);
    dec[b * NPOS + flat0 + aoff] = e;

    unsigned nsb = ~e.x;
    sbuf[b * NPOS + flat0 + aoff] = nsb;
    if (level >= 3) {    // deterministic slots for complete levels 3/4
      unsigned long long key =
          ((unsigned long long)nsb << 32) | (unsigned)((level << 20) | hw);
      gbuf[(size_t)b * CAPTOT + SEG3 + ((level == 3) ? hw : 256 + hw)] = key;
    }
  }
}

// ---------------- kernel 2: fused select+sort, one block per (img,segment) ------
// Replaces hist+cutoff+gather+sort (and the ghist memset). Per block:
//  phase 1: LDS histogram of the level's nsb>>20 prefixes (4096 bins)
//  phase 2: in-block scan + 1000-crossing cutoff B (verbatim proven cutoff logic)
//  phase 3: ballot-compact selected keys into swizzled LDS array (LDS counter;
//           order nondeterministic across waves -> canonicalized by the sort,
//           exactly as the old global-atomic gather was)
//  phase 4: register-blocked bitonic (proven R1 code) -> sorted segment to gbuf,
//           raw count to gcnt (plain store, single writer; no zeroing needed)
// Task 3 skips phases 1-3 and sorts decode's level-3/4 segment.
#define SWQ(q) ((q) ^ (((q) >> 3) & 7))          // pair-index XOR swizzle (bijective)
#define LKI(e) (2 * SWQ((e) >> 1) + ((e) & 1))   // element e -> swizzled u64 index

__device__ __forceinline__ void cmpswap(unsigned long long& a, unsigned long long& b,
                                        bool asc) {
  unsigned long long mn = a < b ? a : b;
  unsigned long long mx = a < b ? b : a;
  a = asc ? mn : mx;
  b = asc ? mx : mn;
}

__global__ __launch_bounds__(256) void selectsort_kernel(const unsigned* __restrict__ sbuf,
                                                         unsigned long long* __restrict__ gbuf,
                                                         int* __restrict__ gcnt) {
  __shared__ unsigned h[NBINS];                  // 16 KB
  __shared__ unsigned long long lk[4096];        // 32 KB, swizzled pair layout
  __shared__ unsigned wpart[4];
  __shared__ int shB;
  __shared__ int sh_cnt;

  int img = blockIdx.x >> 2, sg = blockIdx.x & 3;
  int t = threadIdx.x, lane = t & 63, wv = t >> 6;
  unsigned long long* gb = gbuf + (size_t)img * CAPTOT;

  int base, cap, n, loff;
  if      (sg == 0) { base = 0;    cap = CAP0; n = 16384; loff = 0; }
  else if (sg == 1) { base = SEG1; cap = CAP1; n = 4096;  loff = 16384; }
  else if (sg == 2) { base = SEG2; cap = CAP2; n = 1024;  loff = 20480; }
  else              { base = SEG3; cap = C34;  n = 0;     loff = 0; }

  int c;
  if (sg < 3) {
    // ---- phase 1: LDS histogram ----
    for (int i = t; i < NBINS; i += 256) h[i] = 0;
    if (t == 0) sh_cnt = 0;
    __syncthreads();
    const unsigned* sb = sbuf + img * NPOS + loff;
    for (int i = t; i < n; i += 256) atomicAdd(&h[sb[i] >> 20], 1u);
    __syncthreads();

    // ---- phase 2: scan + cutoff (proven logic, h now in LDS) ----
    unsigned hl[16]; unsigned s = 0;
#pragma unroll
    for (int k = 0; k < 16; ++k) { hl[k] = h[16 * t + k]; s += hl[k]; }
    unsigned incl = s;
    for (int d = 1; d < 64; d <<= 1) {
      unsigned v = __shfl_up(incl, d, 64);
      if (lane >= d) incl += v;
    }
    if (lane == 63) wpart[wv] = incl;
    __syncthreads();
    unsigned woff = 0;
    for (int w = 0; w < wv; ++w) woff += wpart[w];
    unsigned excl = woff + incl - s;
    if (excl < 1000u && excl + s >= 1000u) {     // unique crossing thread (n >= 1000)
      unsigned cum = excl; int B = NBINS - 1;
#pragma unroll
      for (int k = 0; k < 16; ++k) {
        cum += hl[k];
        if (cum >= 1000u) { B = 16 * t + k; break; }
      }
      shB = B;
    }
    __syncthreads();
    int B = shB;

    // ---- phase 3: ballot-compact selected keys into swizzled lk ----
    for (int i = t; i < n; i += 256) {           // n multiple of 256 -> lanes all active
      unsigned nsb = sb[i];
      bool sel = (int)(nsb >> 20) <= B;
      unsigned long long msk = __ballot(sel);
      if (msk) {
        int nsel = __popcll(msk);
        int bas = 0;
        if (lane == 0) bas = atomicAdd(&sh_cnt, nsel);
        bas = __shfl(bas, 0, 64);
        if (sel) {
          int p = bas + __popcll(msk & ((1ULL << lane) - 1ULL));
          if (p < cap) {
            unsigned long long key =
                ((unsigned long long)nsb << 32) | (unsigned)((sg << 20) | i);
            lk[LKI(p)] = key;
          }
        }
      }
    }
    __syncthreads();
    c = min(sh_cnt, cap);
    if (t == 0) gcnt[img * 3 + sg] = sh_cnt;     // raw count; consumers min() (as before)
  } else {
    // ---- task 3: stage decode's complete levels-3/4 segment ----
    for (int i = t; i < C34; i += 256) lk[LKI(i)] = gb[SEG3 + i];
    c = C34;
    __syncthreads();
  }

  // ---- phase 4: register-blocked bitonic sort (proven R1 schedule) ----
  int Pnet = 512;
  while (Pnet < c) Pnet <<= 1;                   // <= 4096
  for (int e = c + t; e < Pnet; e += 256) lk[LKI(e)] = ~0ULL;   // sentinel pad
  __syncthreads();

  ulonglong2* lds2 = (ulonglong2*)lk;
  unsigned long long key[16];
  if (t * 16 < Pnet) {
#pragma unroll
    for (int w = 0; w < 8; ++w) {
      ulonglong2 val = lds2[SWQ(t * 8 + w)];
      key[2 * w]     = val.x;
      key[2 * w + 1] = val.y;
    }
  } else {
#pragma unroll
    for (int v = 0; v < 16; ++v) key[v] = ~0ULL;
  }

  // k = 2,4,8: fully in-register, compile-time directions
#pragma unroll
  for (int kk = 2; kk <= 8; kk <<= 1)
#pragma unroll
    for (int j = kk >> 1; j >= 1; j >>= 1)
#pragma unroll
      for (int v = 0; v < 16; ++v)
        if (!(v & j)) cmpswap(key[v], key[v | j], (v & kk) == 0);

  // k = 16 .. Pnet
  for (int k = 16; k <= Pnet; k <<= 1) {
    bool asc = (t & (k >> 4)) == 0;              // dir of this thread's whole chunk
    for (int j = k >> 1; j >= 16; j >>= 1) {
      int d = j >> 4;                            // partner thread distance
      bool keep_min = ((t & d) == 0) == asc;
      if (d <= 32) {                             // same wave: shuffle exchange
#pragma unroll
        for (int v = 0; v < 16; ++v) {
          unsigned long long p = __shfl_xor(key[v], d, 64);
          unsigned long long mn = key[v] < p ? key[v] : p;
          unsigned long long mx = key[v] < p ? p : key[v];
          key[v] = keep_min ? mn : mx;
        }
      } else {                                   // cross-wave: LDS exchange
        __syncthreads();
#pragma unroll
        for (int w = 0; w < 8; ++w)
          lds2[SWQ(t * 8 + w)] = make_ulonglong2(key[2 * w], key[2 * w + 1]);
        __syncthreads();
        int tp = t ^ d;
#pragma unroll
        for (int w = 0; w < 8; ++w) {
          ulonglong2 pv = lds2[SWQ(tp * 8 + w)];
          unsigned long long a = key[2 * w], b = key[2 * w + 1];
          unsigned long long mn0 = a < pv.x ? a : pv.x, mx0 = a < pv.x ? pv.x : a;
          unsigned long long mn1 = b < pv.y ? b : pv.y, mx1 = b < pv.y ? pv.y : b;
          key[2 * w]     = keep_min ? mn0 : mx0;
          key[2 * w + 1] = keep_min ? mn1 : mx1;
        }
      }
    }
    // tail j = 8..1: in-register, uniform direction
#pragma unroll
    for (int j = 8; j >= 1; j >>= 1)
#pragma unroll
      for (int v = 0; v < 16; ++v)
        if (!(v & j)) cmpswap(key[v], key[v | j], asc);
  }

  // ---- stage out: regs -> LDS -> global (coalesced) ----
  __syncthreads();
  if (t * 16 < Pnet) {
#pragma unroll
    for (int w = 0; w < 8; ++w)
      lds2[SWQ(t * 8 + w)] = make_ulonglong2(key[2 * w], key[2 * w + 1]);
  }
  __syncthreads();
  int npairs = (c + 1) >> 1;                     // may write one sentinel pad (slot < cap, never read)
  ulonglong2* gb2 = (ulonglong2*)(gb + base);    // base is a multiple of 8 -> 16B aligned
  for (int q = t; q < npairs; q += 256) gb2[q] = lds2[SWQ(q)];
}

// ---------------- kernel 3: position via binary search -> sorted pool ----------
__device__ __forceinline__ int lbound(const unsigned long long* __restrict__ a,
                                      int n, unsigned long long x) {
  int lo = 0, len = n;
  while (len > 0) {
    int half = len >> 1;
    int mid = lo + half;
    if (a[mid] < x) { lo = mid + 1; len -= half + 1; }
    else            { len = half; }
  }
  return lo;
}

__global__ __launch_bounds__(256) void pos_kernel(const unsigned long long* __restrict__ gbuf,
                                                  const int* __restrict__ gcnt,
                                                  unsigned long long* __restrict__ pool) {
  int img = blockIdx.x / POS_BPI, bb = blockIdx.x % POS_BPI;
  int e = bb * 256 + threadIdx.x;
  const unsigned long long* gb = gbuf + (size_t)img * CAPTOT;

  int c0 = min(gcnt[img * 3 + 0], CAP0);
  int c1 = min(gcnt[img * 3 + 1], CAP1);
  int c2 = min(gcnt[img * 3 + 2], CAP2);
  int m0 = min(c0, 1000), m1 = min(c1, 1000), m2 = min(c2, 1000);
  int tot = m0 + m1 + m2 + C34;
  if (e >= tot) return;

  int t, i;
  if      (e < m0)           { t = 0; i = e; }
  else if (e < m0 + m1)      { t = 1; i = e - m0; }
  else if (e < m0 + m1 + m2) { t = 2; i = e - m0 - m1; }
  else                       { t = 3; i = e - m0 - m1 - m2; }

  const int off[4] = {0, SEG1, SEG2, SEG3};
  const int cc[4]  = {c0, c1, c2, C34};

  unsigned long long key = gb[off[t] + i];
  int pos = i;                                   // own-segment term: min(rank,1000)=i
#pragma unroll
  for (int u = 0; u < 4; ++u) {
    if (u == t) continue;
    pos += min(lbound(gb + off[u], cc[u], key), 1000);
  }
  pool[img * POOLN + pos] = key;
}

// ---------------- kernel 4: per-image greedy NMS, 64-wide batched --------------
// Exact greedy semantics (R3-verified): per-lane candidates, kept-list broadcast
// test, ffs-order in-batch resolve, exact integer IoU, sorted-desc early exits.
__global__ __launch_bounds__(64) void nms_kernel(const uint4* __restrict__ dec,
                                                 const unsigned long long* __restrict__ pool,
                                                 float* __restrict__ out) {
  __shared__ int4 kbox[MAXDET];
  __shared__ int  karea[MAXDET];
  int img = blockIdx.x;
  int lane = threadIdx.x;

  float* out_s = out + img * MAXDET;
  float* out_c = out + BATCH * MAXDET + img * MAXDET;
  float* out_b = out + 2 * BATCH * MAXDET + img * MAXDET * 4;

  int k = 0;
  bool full = false;

  for (int b0 = 0; b0 < POOLN; b0 += 64) {
    int i = b0 + lane;
    bool inb = i < POOLN;

    float sc = -1.0f;
    int4 bx = make_int4(0, 0, 0, 0);
    int ar = 0;
    unsigned cls = 0;
    if (inb) {
      unsigned long long key = pool[img * POOLN + i];
      unsigned low = (unsigned)key;
      int level = (low >> 20) & 7;
      int idx = low & 0xFFFFF;
      uint4 e = dec[img * NPOS + d_lvl_off[level] + idx];
      sc = __uint_as_float(e.x);
      cls = e.y;
      bx = make_int4((int)(e.z & 0xFFFF), (int)(e.z >> 16),
                     (int)(e.w & 0xFFFF), (int)(e.w >> 16));
      ar = (bx.z - bx.x) * (bx.w - bx.y);
    }

    bool invalid = !(sc > 0.01f);
    if (__all(invalid)) break;          // sorted desc: everything after is invalid too
    bool sup = invalid;

    // vs previously-kept boxes (uniform LDS broadcasts, independent iterations)
    for (int t = 0; t < k; ++t) {
      int4 kb = kbox[t];
      int  ka = karea[t];
      int xx1 = max(bx.x, kb.x), yy1 = max(bx.y, kb.y);
      int xx2 = min(bx.z, kb.z), yy2 = min(bx.w, kb.w);
      int iw = max(xx2 - xx1, 0), ih = max(yy2 - yy1, 0);
      int inter = iw * ih;
      int uni = ar + ka - inter;
      sup = sup || (((long long)inter << 25) > 20132661LL * (long long)uni);
    }

    // in-batch resolve (ascending lane == ascending sorted index)
    unsigned long long alive = __ballot(!sup);
    while (alive) {
      int j = __ffsll(alive) - 1;

      int jx1 = __shfl(bx.x, j, 64), jy1 = __shfl(bx.y, j, 64);
      int jx2 = __shfl(bx.z, j, 64), jy2 = __shfl(bx.w, j, 64);
      int ja  = __shfl(ar,   j, 64);

      if (lane == j) {                  // lane j is kept: record + emit
        kbox[k]  = bx;
        karea[k] = ar;
        out_s[k] = sc;
        out_c[k] = (float)(int)cls;
        out_b[k * 4 + 0] = (float)bx.x;
        out_b[k * 4 + 1] = (float)bx.y;
        out_b[k * 4 + 2] = (float)bx.z;
        out_b[k * 4 + 3] = (float)bx.w;
      }
      ++k;
      if (k == MAXDET) { full = true; break; }

      if (lane > j) {                   // apply j's suppression to later lanes
        int xx1 = max(bx.x, jx1), yy1 = max(bx.y, jy1);
        int xx2 = min(bx.z, jx2), yy2 = min(bx.w, jy2);
        int iw = max(xx2 - xx1, 0), ih = max(yy2 - yy1, 0);
        int inter = iw * ih;
        int uni = ar + ja - inter;
        sup = sup || (((long long)inter << 25) > 20132661LL * (long long)uni);
      }

      unsigned long long himask = (j < 63) ? (~0ULL << (j + 1)) : 0ULL;
      alive = __ballot(!sup) & himask;
    }
    if (full) break;
  }

  for (int s = k + lane; s < MAXDET; s += 64) {
    out_s[s] = -1.0f;
    out_c[s] = -1.0f;
    out_b[s * 4 + 0] = -1.0f;
    out_b[s * 4 + 1] = -1.0f;
    out_b[s * 4 + 2] = -1.0f;
    out_b[s * 4 + 3] = -1.0f;
  }
}

// ---------------- launcher ----------------
extern "C" void kernel_launch(void* const* d_in, const int* in_sizes, int n_in,
                              void* d_out, int out_size, void* d_ws, size_t ws_size,
                              hipStream_t stream) {
  Ptrs args;
  for (int i = 0; i < 20; ++i) args.p[i] = (const float*)d_in[i];

  char* ws = (char*)d_ws;
  uint4* dec = (uint4*)ws;                              // 5,586,944 B
  ws += (size_t)BATCH * NPOS * 16;
  unsigned long long* pool = (unsigned long long*)ws;   // 424,960 B
  ws += (size_t)BATCH * POOLN * 8;
  unsigned long long* gbuf = (unsigned long long*)ws;   // 1,007,616 B (16B-aligned)
  ws += (size_t)BATCH * CAPTOT * 8;
  unsigned* sbuf = (unsigned*)ws;                       // 16*21824*4 = 1,396,736 B
  ws += (size_t)BATCH * NPOS * 4;
  int* gcnt = (int*)ws;                                 // 192 B (plain stores, single writer)
  float* out = (float*)d_out;

  decode_kernel<<<BATCH * DEC_BPI, 256, 0, stream>>>(args, dec, gbuf, sbuf);
  selectsort_kernel<<<BATCH * 4, 256, 0, stream>>>(sbuf, gbuf, gcnt);
  pos_kernel<<<BATCH * POS_BPI, 256, 0, stream>>>(gbuf, gcnt, pool);
  nms_kernel<<<BATCH, 64, 0, stream>>>(dec, pool, out);
}

// Round 7
// 266.839 us; speedup vs baseline: 1.1721x; 1.1557x over previous
//
#include <hip/hip_runtime.h>
#include <stdint.h>

// ---------------- problem constants ----------------
#define BATCH 16
#define NCLS 80
#define NPOS 21824            // 16384+4096+1024+256+64
#define POOLN 3320            // 1000+1000+1000+256+64
#define MAXDET 100

// superset segment capacities (multiples of 8)
#define CAP0 4096
#define CAP1 2432
#define CAP2 1024
#define C34 320
#define SEG1 (CAP0)                    // 4096
#define SEG2 (CAP0 + CAP1)             // 6528
#define SEG3 (CAP0 + CAP1 + CAP2)      // 7552
#define CAPTOT (SEG3 + C34)            // 7872

#define DEC_BPI 341                    // 21824/64 anchors-per-block blocks per image
#define POS_BPI 13                     // 13 x 256 = 3328 >= 3320 pool elements
#define NBINS 4096                     // digit = nsb >> 20 (12-bit key prefix)

__device__ const int d_lvl_off[5] = {0, 16384, 20480, 21504, 21760};
__device__ const int d_lvl_hw[5]  = {16384, 4096, 1024, 256, 64};

struct Ptrs { const float* p[20]; };

__device__ __forceinline__ void map_lvl(int r, int& level, int& hw) {
  if      (r < 16384) { level = 0; hw = r; }
  else if (r < 20480) { level = 1; hw = r - 16384; }
  else if (r < 21504) { level = 2; hw = r - 20480; }
  else if (r < 21760) { level = 3; hw = r - 21504; }
  else                { level = 4; hw = r - 21760; }
}

// key = (nsb)<<32 | (level<<20) | hw with nsb = ~score_bits; ascending ==
// (score desc, level asc, idx asc). Unique per image; ~0ULL is a strictly-greater
// sentinel. digit = nsb >> 20 is a 12-bit key PREFIX -> {digit <= B} downward-closed.

// ---------------- kernel 1: decode (R4 coalesced two-phase argmax, BW-bound) ----
__global__ __launch_bounds__(256) void decode_kernel(Ptrs args, uint4* __restrict__ dec,
                                                     unsigned long long* __restrict__ gbuf,
                                                     unsigned* __restrict__ sbuf) {
  __shared__ float2 sm[1280];               // (chunk max, chunk argmax-bits), 10 KB
  int b  = blockIdx.x / DEC_BPI;
  int bb = blockIdx.x - b * DEC_BPI;
  int t = threadIdx.x;

  int flat0 = bb * 64;                      // level boundaries are all multiples of 64
  int level, hw0;
  map_lvl(flat0, level, hw0);
  int HW = d_lvl_hw[level];

  const float* cls = args.p[level * 4 + 0];
  const float* reg = args.p[level * 4 + 1];
  const float* ctr = args.p[level * 4 + 2];
  const float* pos = args.p[level * 4 + 3];

  // ---- phase 1: coalesced load + per-chunk argmax ----
  const float4* c4 = (const float4*)(cls + ((long)b * HW + hw0) * NCLS);
#pragma unroll
  for (int w = 0; w < 5; ++w) {
    int f = t + 256 * w;                    // float4 index in [0,1280)
    float4 v = c4[f];
    int q = f % 20;                         // chunk within anchor -> classes 4q..4q+3
    float m = -1e30f; int am = 4 * q;
    if (v.x > m) { m = v.x; am = 4 * q + 0; }
    if (v.y > m) { m = v.y; am = 4 * q + 1; }
    if (v.z > m) { m = v.z; am = 4 * q + 2; }
    if (v.w > m) { m = v.w; am = 4 * q + 3; }
    sm[f] = make_float2(m, __int_as_float(am));
  }
  __syncthreads();

  // ---- phase 2: fold 5 chunks per lane (ascending), then 4-lane shfl combine ----
  int aoff = t >> 2, r = t & 3;
  int base = aoff * 20 + 5 * r;
  float2 c0 = sm[base];
  float m = c0.x; int am = __float_as_int(c0.y);
#pragma unroll
  for (int i = 1; i < 5; ++i) {
    float2 cc = sm[base + i];
    int oa = __float_as_int(cc.y);
    if (cc.x > m || (cc.x == m && oa < am)) { m = cc.x; am = oa; }
  }
#pragma unroll
  for (int d = 1; d <= 2; d <<= 1) {
    float om = __shfl_xor(m, d, 64);
    int   oa = __shfl_xor(am, d, 64);
    if (om > m || (om == m && oa < am)) { m = om; am = oa; }
  }

  if (r == 0) {
    int hw = hw0 + aoff;
    long abase = (long)b * HW + hw;
    float4 rg = *(const float4*)(reg + abase * 4);
    float  ct = ctr[abase];
    float2 ps = ((const float2*)pos)[abase];

    float e0 = expf(rg.x), e1 = expf(rg.y), e2 = expf(rg.z), e3 = expf(rg.w);
    int x1 = (int)(ps.x - e0);   // C truncation == .astype(int32)
    int y1 = (int)(ps.y - e1);
    int x2 = (int)(ps.x + e2);
    int y2 = (int)(ps.y + e3);
    x1 = max(x1, 0); y1 = max(y1, 0);
    x2 = min(x2, 1023); y2 = min(y2, 1023);

    float sigm = 1.0f / (1.0f + expf(-m));
    float sigc = 1.0f / (1.0f + expf(-ct));
    float score = sqrtf(sigm * sigc);

    uint4 e;
    e.x = __float_as_uint(score);
    e.y = (unsigned)am;
    e.z = (unsigned)(x1 & 0xFFFF) | ((unsigned)y1 << 16);
    e.w = (unsigned)(x2 & 0xFFFF) | ((unsigned)y2 << 16);
    dec[b * NPOS + flat0 + aoff] = e;

    unsigned nsb = ~e.x;
    sbuf[b * NPOS + flat0 + aoff] = nsb;
    if (level >= 3) {    // deterministic slots for complete levels 3/4
      unsigned long long key =
          ((unsigned long long)nsb << 32) | (unsigned)((level << 20) | hw);
      gbuf[(size_t)b * CAPTOT + SEG3 + ((level == 3) ? hw : 256 + hw)] = key;
    }
  }
}

// ---------------- kernel 2: fused select+sort, 1024 threads/(img,segment) ------
// sg=0: hist(16 iter, reg-prefetched) + 16-wave scan/cutoff + compact(16 iter)
//       + bitonic.  sg=1/2: NO selection — sort ALL n elements (sorted prefix is
//       downward-closed and contains the 1000 smallest, so min(lbound,1000) and
//       the first-1000 candidate set are identical to bin-cutoff selection).
//       Output first cap. sg=3: sort decode's level-3/4 segment.
// Bitonic re-blocked V=4 x 1024 threads, same comparator/sentinels as proven R1.
#define SWQ(q) ((q) ^ (((q) >> 3) & 7))          // pair-index XOR swizzle (bijective)
#define LKI(e) (2 * SWQ((e) >> 1) + ((e) & 1))   // element e -> swizzled u64 index

__device__ __forceinline__ void cmpswap(unsigned long long& a, unsigned long long& b,
                                        bool asc) {
  unsigned long long mn = a < b ? a : b;
  unsigned long long mx = a < b ? b : a;
  a = asc ? mn : mx;
  b = asc ? mx : mn;
}

__global__ __launch_bounds__(1024) void selectsort_kernel(const unsigned* __restrict__ sbuf,
                                                          unsigned long long* __restrict__ gbuf,
                                                          int* __restrict__ gcnt) {
  __shared__ unsigned h[NBINS];                  // 16 KB
  __shared__ unsigned long long lk[4096];        // 32 KB, swizzled pair layout
  __shared__ unsigned wpart[16];
  __shared__ int shB;
  __shared__ int sh_cnt;

  int img = blockIdx.x >> 2, sg = blockIdx.x & 3;
  int t = threadIdx.x, lane = t & 63, wv = t >> 6;
  unsigned long long* gb = gbuf + (size_t)img * CAPTOT;

  int c, base, cap;
  if (sg == 0) {
    base = 0; cap = CAP0;
    const unsigned* sb = sbuf + img * NPOS;

    // ---- phase 1: LDS histogram (16384 = 16 x 1024, loads prefetched) ----
    for (int i = t; i < NBINS; i += 1024) h[i] = 0;
    if (t == 0) sh_cnt = 0;
    __syncthreads();
    unsigned dig[16];
#pragma unroll
    for (int w = 0; w < 16; ++w) dig[w] = sb[t + 1024 * w] >> 20;
#pragma unroll
    for (int w = 0; w < 16; ++w) atomicAdd(&h[dig[w]], 1u);
    __syncthreads();

    // ---- phase 2: 16-wave scan + 1000-crossing cutoff (4 bins/thread) ----
    unsigned hl[4]; unsigned s = 0;
#pragma unroll
    for (int k2 = 0; k2 < 4; ++k2) { hl[k2] = h[4 * t + k2]; s += hl[k2]; }
    unsigned incl = s;
    for (int d = 1; d < 64; d <<= 1) {
      unsigned v = __shfl_up(incl, d, 64);
      if (lane >= d) incl += v;
    }
    if (lane == 63) wpart[wv] = incl;
    __syncthreads();
    unsigned woff = 0;
    for (int w = 0; w < wv; ++w) woff += wpart[w];
    unsigned excl = woff + incl - s;
    if (excl < 1000u && excl + s >= 1000u) {     // unique crossing thread (n >= 1000)
      unsigned cum = excl; int B = NBINS - 1;
#pragma unroll
      for (int k2 = 0; k2 < 4; ++k2) {
        cum += hl[k2];
        if (cum >= 1000u) { B = 4 * t + k2; break; }
      }
      shB = B;
    }
    __syncthreads();
    int B = shB;

    // ---- phase 3: ballot-compact selected keys into swizzled lk ----
    unsigned nsbv[16];
#pragma unroll
    for (int w = 0; w < 16; ++w) nsbv[w] = sb[t + 1024 * w];
#pragma unroll
    for (int w = 0; w < 16; ++w) {
      int i = t + 1024 * w;
      unsigned nsb = nsbv[w];
      bool sel = (int)(nsb >> 20) <= B;
      unsigned long long msk = __ballot(sel);
      if (msk) {
        int nsel = __popcll(msk);
        int bas = 0;
        if (lane == 0) bas = atomicAdd(&sh_cnt, nsel);
        bas = __shfl(bas, 0, 64);
        if (sel) {
          int p = bas + __popcll(msk & ((1ULL << lane) - 1ULL));
          if (p < cap) {
            unsigned long long key = ((unsigned long long)nsb << 32) | (unsigned)i;
            lk[LKI(p)] = key;                    // level 0: (0<<20)|i == i
          }
        }
      }
    }
    __syncthreads();
    c = min(sh_cnt, cap);
    if (t == 0) gcnt[img * 3] = sh_cnt;          // raw count; consumers min()
  } else if (sg < 3) {
    // ---- levels 1/2: no selection — sort ALL n, output first cap ----
    int n, loff;
    if (sg == 1) { base = SEG1; cap = CAP1; n = 4096; loff = 16384; }
    else         { base = SEG2; cap = CAP2; n = 1024; loff = 20480; }
    const unsigned* sb = sbuf + img * NPOS + loff;
    for (int i = t; i < n; i += 1024)
      lk[LKI(i)] = ((unsigned long long)sb[i] << 32) | (unsigned)((sg << 20) | i);
    c = n;
    if (t == 0) gcnt[img * 3 + sg] = n;          // min(n,cap) applied by consumers
  } else {
    // ---- task 3: decode's complete levels-3/4 segment ----
    base = SEG3; cap = C34;
    for (int i = t; i < C34; i += 1024) lk[LKI(i)] = gb[SEG3 + i];
    c = C34;
  }

  // ---- phase 4: bitonic sort, V=4 x 1024 threads (same network semantics) ----
  int Pnet = 512;
  while (Pnet < c) Pnet <<= 1;                   // <= 4096
  for (int e = c + t; e < Pnet; e += 1024) lk[LKI(e)] = ~0ULL;   // sentinel pad
  __syncthreads();

  ulonglong2* lds2 = (ulonglong2*)lk;
  unsigned long long key[4];
  if (t * 4 < Pnet) {
    ulonglong2 v0 = lds2[SWQ(2 * t)], v1 = lds2[SWQ(2 * t + 1)];
    key[0] = v0.x; key[1] = v0.y; key[2] = v1.x; key[3] = v1.y;
  } else {
    key[0] = key[1] = key[2] = key[3] = ~0ULL;
  }

  // k = 2: in-register, dirs from element bits (e&2)
  cmpswap(key[0], key[1], true);
  cmpswap(key[2], key[3], false);

  // k = 4 .. Pnet: asc = ((4t & k)==0) == ((t & (k>>2))==0)
  for (int k = 4; k <= Pnet; k <<= 1) {
    bool asc = (t & (k >> 2)) == 0;
    for (int j = k >> 1; j >= 4; j >>= 1) {
      int d = j >> 2;                            // partner thread distance
      bool keep_min = ((t & d) == 0) == asc;
      if (d <= 32) {                             // same wave: shuffle exchange
#pragma unroll
        for (int v = 0; v < 4; ++v) {
          unsigned long long p = __shfl_xor(key[v], d, 64);
          unsigned long long mn = key[v] < p ? key[v] : p;
          unsigned long long mx = key[v] < p ? p : key[v];
          key[v] = keep_min ? mn : mx;
        }
      } else {                                   // cross-wave: LDS exchange
        __syncthreads();
        lds2[SWQ(2 * t)]     = make_ulonglong2(key[0], key[1]);
        lds2[SWQ(2 * t + 1)] = make_ulonglong2(key[2], key[3]);
        __syncthreads();
        int tp = t ^ d;
        ulonglong2 p0 = lds2[SWQ(2 * tp)], p1 = lds2[SWQ(2 * tp + 1)];
        unsigned long long pv0 = p0.x, pv1 = p0.y, pv2 = p1.x, pv3 = p1.y;
        unsigned long long mn, mx;
        mn = key[0] < pv0 ? key[0] : pv0; mx = key[0] < pv0 ? pv0 : key[0];
        key[0] = keep_min ? mn : mx;
        mn = key[1] < pv1 ? key[1] : pv1; mx = key[1] < pv1 ? pv1 : key[1];
        key[1] = keep_min ? mn : mx;
        mn = key[2] < pv2 ? key[2] : pv2; mx = key[2] < pv2 ? pv2 : key[2];
        key[2] = keep_min ? mn : mx;
        mn = key[3] < pv3 ? key[3] : pv3; mx = key[3] < pv3 ? pv3 : key[3];
        key[3] = keep_min ? mn : mx;
      }
    }
    // tail j = 2,1: in-register, uniform direction
    cmpswap(key[0], key[2], asc); cmpswap(key[1], key[3], asc);
    cmpswap(key[0], key[1], asc); cmpswap(key[2], key[3], asc);
  }

  // ---- stage out: regs -> LDS -> global (coalesced) ----
  __syncthreads();
  lds2[SWQ(2 * t)]     = make_ulonglong2(key[0], key[1]);
  lds2[SWQ(2 * t + 1)] = make_ulonglong2(key[2], key[3]);
  __syncthreads();
  int c_out = min(c, cap);
  int npairs = (c_out + 1) >> 1;                 // odd c may write one sentinel pad (< cap, never read)
  ulonglong2* gb2 = (ulonglong2*)(gb + base);    // base is a multiple of 8 -> 16B aligned
  for (int q = t; q < npairs; q += 1024) gb2[q] = lds2[SWQ(q)];
}

// ---------------- kernel 3: position via binary search -> sorted pool ----------
__device__ __forceinline__ int lbound(const unsigned long long* __restrict__ a,
                                      int n, unsigned long long x) {
  int lo = 0, len = n;
  while (len > 0) {
    int half = len >> 1;
    int mid = lo + half;
    if (a[mid] < x) { lo = mid + 1; len -= half + 1; }
    else            { len = half; }
  }
  return lo;
}

__global__ __launch_bounds__(256) void pos_kernel(const unsigned long long* __restrict__ gbuf,
                                                  const int* __restrict__ gcnt,
                                                  unsigned long long* __restrict__ pool) {
  int img = blockIdx.x / POS_BPI, bb = blockIdx.x % POS_BPI;
  int e = bb * 256 + threadIdx.x;
  const unsigned long long* gb = gbuf + (size_t)img * CAPTOT;

  int c0 = min(gcnt[img * 3 + 0], CAP0);
  int c1 = min(gcnt[img * 3 + 1], CAP1);
  int c2 = min(gcnt[img * 3 + 2], CAP2);
  int m0 = min(c0, 1000), m1 = min(c1, 1000), m2 = min(c2, 1000);
  int tot = m0 + m1 + m2 + C34;
  if (e >= tot) return;

  int t, i;
  if      (e < m0)           { t = 0; i = e; }
  else if (e < m0 + m1)      { t = 1; i = e - m0; }
  else if (e < m0 + m1 + m2) { t = 2; i = e - m0 - m1; }
  else                       { t = 3; i = e - m0 - m1 - m2; }

  const int off[4] = {0, SEG1, SEG2, SEG3};
  const int cc[4]  = {c0, c1, c2, C34};

  unsigned long long key = gb[off[t] + i];
  int pos = i;                                   // own-segment term: min(rank,1000)=i
#pragma unroll
  for (int u = 0; u < 4; ++u) {
    if (u == t) continue;
    pos += min(lbound(gb + off[u], cc[u], key), 1000);
  }
  pool[img * POOLN + pos] = key;
}

// ---------------- kernel 4: per-image greedy NMS, 64-wide batched --------------
// Exact greedy semantics (R3-verified): per-lane candidates, kept-list broadcast
// test, ffs-order in-batch resolve, exact integer IoU, sorted-desc early exits.
__global__ __launch_bounds__(64) void nms_kernel(const uint4* __restrict__ dec,
                                                 const unsigned long long* __restrict__ pool,
                                                 float* __restrict__ out) {
  __shared__ int4 kbox[MAXDET];
  __shared__ int  karea[MAXDET];
  int img = blockIdx.x;
  int lane = threadIdx.x;

  float* out_s = out + img * MAXDET;
  float* out_c = out + BATCH * MAXDET + img * MAXDET;
  float* out_b = out + 2 * BATCH * MAXDET + img * MAXDET * 4;

  int k = 0;
  bool full = false;

  for (int b0 = 0; b0 < POOLN; b0 += 64) {
    int i = b0 + lane;
    bool inb = i < POOLN;

    float sc = -1.0f;
    int4 bx = make_int4(0, 0, 0, 0);
    int ar = 0;
    unsigned cls = 0;
    if (inb) {
      unsigned long long key = pool[img * POOLN + i];
      unsigned low = (unsigned)key;
      int level = (low >> 20) & 7;
      int idx = low & 0xFFFFF;
      uint4 e = dec[img * NPOS + d_lvl_off[level] + idx];
      sc = __uint_as_float(e.x);
      cls = e.y;
      bx = make_int4((int)(e.z & 0xFFFF), (int)(e.z >> 16),
                     (int)(e.w & 0xFFFF), (int)(e.w >> 16));
      ar = (bx.z - bx.x) * (bx.w - bx.y);
    }

    bool invalid = !(sc > 0.01f);
    if (__all(invalid)) break;          // sorted desc: everything after is invalid too
    bool sup = invalid;

    // vs previously-kept boxes (uniform LDS broadcasts, independent iterations)
    for (int t = 0; t < k; ++t) {
      int4 kb = kbox[t];
      int  ka = karea[t];
      int xx1 = max(bx.x, kb.x), yy1 = max(bx.y, kb.y);
      int xx2 = min(bx.z, kb.z), yy2 = min(bx.w, kb.w);
      int iw = max(xx2 - xx1, 0), ih = max(yy2 - yy1, 0);
      int inter = iw * ih;
      int uni = ar + ka - inter;
      sup = sup || (((long long)inter << 25) > 20132661LL * (long long)uni);
    }

    // in-batch resolve (ascending lane == ascending sorted index)
    unsigned long long alive = __ballot(!sup);
    while (alive) {
      int j = __ffsll(alive) - 1;

      int jx1 = __shfl(bx.x, j, 64), jy1 = __shfl(bx.y, j, 64);
      int jx2 = __shfl(bx.z, j, 64), jy2 = __shfl(bx.w, j, 64);
      int ja  = __shfl(ar,   j, 64);

      if (lane == j) {                  // lane j is kept: record + emit
        kbox[k]  = bx;
        karea[k] = ar;
        out_s[k] = sc;
        out_c[k] = (float)(int)cls;
        out_b[k * 4 + 0] = (float)bx.x;
        out_b[k * 4 + 1] = (float)bx.y;
        out_b[k * 4 + 2] = (float)bx.z;
        out_b[k * 4 + 3] = (float)bx.w;
      }
      ++k;
      if (k == MAXDET) { full = true; break; }

      if (lane > j) {                   // apply j's suppression to later lanes
        int xx1 = max(bx.x, jx1), yy1 = max(bx.y, jy1);
        int xx2 = min(bx.z, jx2), yy2 = min(bx.w, jy2);
        int iw = max(xx2 - xx1, 0), ih = max(yy2 - yy1, 0);
        int inter = iw * ih;
        int uni = ar + ja - inter;
        sup = sup || (((long long)inter << 25) > 20132661LL * (long long)uni);
      }

      unsigned long long himask = (j < 63) ? (~0ULL << (j + 1)) : 0ULL;
      alive = __ballot(!sup) & himask;
    }
    if (full) break;
  }

  for (int s = k + lane; s < MAXDET; s += 64) {
    out_s[s] = -1.0f;
    out_c[s] = -1.0f;
    out_b[s * 4 + 0] = -1.0f;
    out_b[s * 4 + 1] = -1.0f;
    out_b[s * 4 + 2] = -1.0f;
    out_b[s * 4 + 3] = -1.0f;
  }
}

// ---------------- launcher ----------------
extern "C" void kernel_launch(void* const* d_in, const int* in_sizes, int n_in,
                              void* d_out, int out_size, void* d_ws, size_t ws_size,
                              hipStream_t stream) {
  Ptrs args;
  for (int i = 0; i < 20; ++i) args.p[i] = (const float*)d_in[i];

  char* ws = (char*)d_ws;
  uint4* dec = (uint4*)ws;                              // 5,586,944 B
  ws += (size_t)BATCH * NPOS * 16;
  unsigned long long* pool = (unsigned long long*)ws;   // 424,960 B
  ws += (size_t)BATCH * POOLN * 8;
  unsigned long long* gbuf = (unsigned long long*)ws;   // 1,007,616 B (16B-aligned)
  ws += (size_t)BATCH * CAPTOT * 8;
  unsigned* sbuf = (unsigned*)ws;                       // 16*21824*4 = 1,396,736 B
  ws += (size_t)BATCH * NPOS * 4;
  int* gcnt = (int*)ws;                                 // 192 B (plain stores, single writer)
  float* out = (float*)d_out;

  decode_kernel<<<BATCH * DEC_BPI, 256, 0, stream>>>(args, dec, gbuf, sbuf);
  selectsort_kernel<<<BATCH * 4, 1024, 0, stream>>>(sbuf, gbuf, gcnt);
  pos_kernel<<<BATCH * POS_BPI, 256, 0, stream>>>(gbuf, gcnt, pool);
  nms_kernel<<<BATCH, 64, 0, stream>>>(dec, pool, out);
}